// Round 6
// baseline (544.501 us; speedup 1.0000x reference)
//
#include <hip/hip_runtime.h>
#include <math.h>

#define C 64
#define NL 30
#define T 16384
#define B 4

typedef __bf16 bf16_t;
typedef __bf16 bf16x8 __attribute__((ext_vector_type(8)));
typedef __bf16 bf16x4 __attribute__((ext_vector_type(4)));
typedef float f32x4 __attribute__((ext_vector_type(4)));

typedef const __attribute__((address_space(1))) unsigned int glb_u32;
typedef __attribute__((address_space(3))) unsigned int lds_u32;

constexpr float INV_SQRT2   = 0.70710678118654752440f;
constexpr float INV_SQRT_NL = 0.18257418583505537115f; // 1/sqrt(30)

__device__ __forceinline__ float fsig(float x) {
    return __builtin_amdgcn_rcpf(1.f + __builtin_amdgcn_exp2f(-1.44269504089f * x));
}
__device__ __forceinline__ float ftanh(float x) {
    return fmaf(2.f, __builtin_amdgcn_rcpf(1.f + __builtin_amdgcn_exp2f(-2.88539008178f * x)), -1.f);
}
// XOR swizzle for 128-byte-row LDS tiles (G4): byte ^= ((row&7)<<4)
__device__ __forceinline__ int swz(int off) { return off ^ ((off >> 3) & 0x70); }

// ---------------------------------------------------------------------------
// Pack weights to bf16 K-contiguous rows:
//   convpk[l][oc][k], k = tap*64+ic ; oppk[l][oc][ic] ; skpk[oc][ic]*1/sqrt(30)
// ---------------------------------------------------------------------------
__global__ void pack_weights(const float* __restrict__ dw_W,
                             const float* __restrict__ op_W,
                             const float* __restrict__ sk_W,
                             bf16_t* __restrict__ convpk,
                             bf16_t* __restrict__ oppk,
                             bf16_t* __restrict__ skpk) {
    int idx = blockIdx.x * 256 + threadIdx.x;
    const int ndw = NL * 128 * 192;
    const int nop = NL * 128 * 64;
    if (idx < ndw) {
        int k = idx % 192; int r = idx / 192;
        int oc = r % 128;  int l = r / 128;
        int tap = k >> 6, ic = k & 63;
        convpk[idx] = (bf16_t)dw_W[((l * 128 + oc) * 64 + ic) * 3 + tap];
    } else if (idx < ndw + nop) {
        oppk[idx - ndw] = (bf16_t)op_W[idx - ndw];
    } else if (idx < ndw + nop + 4096) {
        int j = idx - ndw - nop;
        skpk[j] = (bf16_t)(sk_W[j] * INV_SQRT_NL);
    }
}

// ---------------------------------------------------------------------------
// Cond: emb -> p1 (silu). grid (B, 8): block owns 64 outputs, 4-way split-K.
// ---------------------------------------------------------------------------
__global__ void cond_embp1(const int* __restrict__ step,
                           const float* __restrict__ p1_W, const float* __restrict__ p1_b,
                           float* __restrict__ h1out) {
    __shared__ float e[128];
    __shared__ float red[256];
    int b = blockIdx.x, blk = blockIdx.y, tid = threadIdx.x;
    int s = step[b];
    if (tid < 128) {
        int d = tid & 63;
        float tf = (float)s * powf(10.f, (float)d * 4.f / 63.f);
        double td = (double)tf;
        e[tid] = (tid < 64) ? (float)sin(td) : (float)cos(td);
    }
    __syncthreads();
    int ol = tid >> 2, q = tid & 3;
    int o = blk * 64 + ol;
    const float4* wr = (const float4*)(p1_W + o * 128 + q * 32);
    const float4* ev = (const float4*)(e + q * 32);
    float a = 0.f;
    #pragma unroll
    for (int j = 0; j < 8; ++j) {
        float4 wv = wr[j]; float4 xv = ev[j];
        a = fmaf(wv.x, xv.x, a); a = fmaf(wv.y, xv.y, a);
        a = fmaf(wv.z, xv.z, a); a = fmaf(wv.w, xv.w, a);
    }
    red[tid] = a;
    __syncthreads();
    if (q == 0) {
        float v = red[tid] + red[tid + 1] + red[tid + 2] + red[tid + 3] + p1_b[o];
        h1out[b * 512 + o] = v / (1.f + expf(-v));
    }
}

// ---------------------------------------------------------------------------
// Cond: p2 (silu). grid (B, 8): block owns 64 outputs, 4-way split-K (K=512).
// ---------------------------------------------------------------------------
__global__ void cond_p2(const float* __restrict__ h1,
                        const float* __restrict__ p2_W, const float* __restrict__ p2_b,
                        float* __restrict__ h2out) {
    __shared__ float red[256];
    int b = blockIdx.x, blk = blockIdx.y, tid = threadIdx.x;
    int ol = tid >> 2, q = tid & 3;
    int o = blk * 64 + ol;
    const float4* wr = (const float4*)(p2_W + o * 512 + q * 128);
    const float4* hv = (const float4*)(h1 + b * 512 + q * 128);
    float a = 0.f;
    #pragma unroll 8
    for (int j = 0; j < 32; ++j) {
        float4 wv = wr[j]; float4 xv = hv[j];
        a = fmaf(wv.x, xv.x, a); a = fmaf(wv.y, xv.y, a);
        a = fmaf(wv.z, xv.z, a); a = fmaf(wv.w, xv.w, a);
    }
    red[tid] = a;
    __syncthreads();
    if (q == 0) {
        float v = red[tid] + red[tid + 1] + red[tid + 2] + red[tid + 3] + p2_b[o];
        h2out[b * 512 + o] = v / (1.f + expf(-v));
    }
}

// ---------------------------------------------------------------------------
// Fused: cond projection + fold into conv bias.
//   cond[c]       = dp_W[l] @ h2[b] + dp_b[l]         (in LDS only)
//   bias2[l][b][o]= dw_b[l][o] + sum_k convpk[l][o][k] * cond[k&63]
// grid (NL, B), 256 threads.
// ---------------------------------------------------------------------------
__global__ void cond_stage2b(const float* __restrict__ h2,
                             const float* __restrict__ dp_W, const float* __restrict__ dp_b,
                             const bf16_t* __restrict__ convpk,
                             const float* __restrict__ dw_b,
                             float* __restrict__ bias2) {
    __shared__ float red[256];
    __shared__ float cond_s[64];
    int l = blockIdx.x, b = blockIdx.y;
    int tid = threadIdx.x;
    {
        int o = tid >> 2, q = tid & 3;
        const float4* wr = (const float4*)(dp_W + ((size_t)l * C + o) * 512 + q * 128);
        const float4* h = (const float4*)(h2 + b * 512 + q * 128);
        float a = 0.f;
        #pragma unroll 8
        for (int j = 0; j < 32; ++j) {
            float4 wv = wr[j]; float4 hv = h[j];
            a = fmaf(wv.x, hv.x, a); a = fmaf(wv.y, hv.y, a);
            a = fmaf(wv.z, hv.z, a); a = fmaf(wv.w, hv.w, a);
        }
        red[tid] = a;
        __syncthreads();
        if (q == 0)
            cond_s[o] = red[tid] + red[tid + 1] + red[tid + 2] + red[tid + 3] + dp_b[l * C + o];
    }
    __syncthreads();
    // fold: oc = tid&127, kh = tid>>7 handles k in [kh*96, kh*96+96)
    int oc = tid & 127, kh = tid >> 7;
    const bf16_t* wr = convpk + ((size_t)l * 128 + oc) * 192 + kh * 96;
    float a = kh ? 0.f : dw_b[l * 128 + oc];
    #pragma unroll
    for (int j = 0; j < 96; ++j)
        a = fmaf((float)wr[j], cond_s[(kh * 96 + j) & 63], a);
    __syncthreads();
    red[tid] = a;
    __syncthreads();
    if (tid < 128)
        bias2[(l * B + b) * 128 + tid] = red[tid] + red[tid + 128];
}

// ---------------------------------------------------------------------------
// Input 1x1 conv + ReLU -> x[b][t][c] bf16. Thread handles 8 channels.
// ---------------------------------------------------------------------------
__global__ void in_conv(const float* __restrict__ audio,
                        const float* __restrict__ in_W, const float* __restrict__ in_b,
                        bf16_t* __restrict__ x) {
    int idx = blockIdx.x * 256 + threadIdx.x;   // over B*T*8
    int cb = idx & 7;
    int t = (idx >> 3) & (T - 1);
    int b = idx >> 17;
    float av = audio[b * T + t];
    bf16x8 o;
    #pragma unroll
    for (int j = 0; j < 8; ++j) {
        int c = cb * 8 + j;
        o[j] = (bf16_t)fmaxf(fmaf(in_W[c], av, in_b[c]), 0.f);
    }
    *(bf16x8*)(x + ((size_t)b * T + t) * 64 + cb * 8) = o;
}

// ---------------------------------------------------------------------------
// One residual layer. x layout [b][t][c] bf16. 512 thr = 8 waves, 128-t tile.
// Waves 0-3 compute t-half 0; waves 4-7 compute t-half 1 (CONCURRENT halves).
// Within a half, wave wq owns conv rows {wq*16..+16} (gate) and
// {64+wq*16..+16} (filt): gate/filt pair in the same lane -> no exchange.
// Whole tile staged once via global_load_lds(16B), swizzle on the GLOBAL
// source (c16 ^= row&7), linear LDS dest; OOB taps read a zeroed page.
// LDS: 2 halves x 3 tap slices [64t][64c] bf16 (48KB) + 2 z tiles (16KB).
// Only TWO barriers per block.
// ---------------------------------------------------------------------------
__global__ __launch_bounds__(512, 4) void layer_kernel(
    const bf16_t* __restrict__ x_in, bf16_t* __restrict__ x_out, bf16_t* __restrict__ skip,
    const bf16_t* __restrict__ convpk, const bf16_t* __restrict__ oppk,
    const float* __restrict__ bias2, const float* __restrict__ op_b,
    const bf16_t* __restrict__ zpage,
    int layer, int dil, int first)
{
    __shared__ uint4 smem_u[4096];                       // 65536 B
    char* sm = (char*)smem_u;

    int tid = threadIdx.x;
    int w8 = __builtin_amdgcn_readfirstlane(tid >> 6);   // wave id 0..7
    int wq = w8 & 3;                                     // m-split id
    int h  = w8 >> 2;                                    // t-half id
    int l = tid & 63;
    int lr = l & 15;
    int g = l >> 4;
    int b = blockIdx.y;
    int tbase = blockIdx.x * 128;
    const bf16_t* xb = x_in + (size_t)b * T * 64;

    // ---- stage whole 128-t tile: 6 x global_load_lds(16B) per thread -----
    // chunk idx = it*512 + tid ; layout byte = it*8192 + tid*16
    //   = (it/3)*24576(half) + (it%3)*8192(slice) + (tid>>3)*128(row) + (tid&7)*16
    #pragma unroll
    for (int it = 0; it < 6; ++it) {
        int hh = it / 3;                 // staged half
        int slice = it % 3;
        int row = tid >> 3;              // 0..63  (= w8*8 + (l>>3))
        int c16 = l & 7;
        int ts = tbase + hh * 64 + row + (slice - 1) * dil;
        int c16s = c16 ^ (row & 7);      // swizzle on SOURCE
        const bf16_t* src = ((unsigned)ts < (unsigned)T)
            ? (xb + (size_t)ts * 64 + c16s * 8)
            : (zpage + c16s * 8);
        __builtin_amdgcn_global_load_lds(
            (glb_u32*)src,
            (lds_u32*)(sm + it * 8192 + w8 * 1024),      // wave-uniform base
            16, 0, 0);
    }

    // ---- A fragments (conv weights) in registers -------------------------
    bf16x8 cA[2][6];
    const bf16_t* cw = convpk + (size_t)layer * 128 * 192;
    #pragma unroll
    for (int mf = 0; mf < 2; ++mf)
        #pragma unroll
        for (int kf = 0; kf < 6; ++kf)
            cA[mf][kf] = *(const bf16x8*)(cw + (mf * 64 + wq * 16 + lr) * 192 + kf * 32 + g * 8);

    // ---- conv accumulators init with cond-folded bias --------------------
    f32x4 acc[2][4];
    const float* b2 = bias2 + (layer * B + b) * 128;
    #pragma unroll
    for (int mf = 0; mf < 2; ++mf) {
        f32x4 bv;
        #pragma unroll
        for (int r = 0; r < 4; ++r) bv[r] = b2[mf * 64 + wq * 16 + g * 4 + r];
        #pragma unroll
        for (int nf = 0; nf < 4; ++nf) acc[mf][nf] = bv;
    }
    __syncthreads();                                      // barrier 1: stage done

    // ---- conv GEMM: K = 3 taps x 64 c ------------------------------------
    int hbase = h * 24576;
    #pragma unroll
    for (int kf = 0; kf < 6; ++kf) {
        int tap = kf >> 1;
        int kc = (kf & 1) * 32;
        bf16x8 Bf[4];
        #pragma unroll
        for (int nf = 0; nf < 4; ++nf) {
            int off = hbase + tap * 8192 + (nf * 16 + lr) * 128 + (kc + g * 8) * 2;
            Bf[nf] = *(const bf16x8*)(sm + swz(off));
        }
        #pragma unroll
        for (int mf = 0; mf < 2; ++mf)
            #pragma unroll
            for (int nf = 0; nf < 4; ++nf)
                acc[mf][nf] = __builtin_amdgcn_mfma_f32_16x16x32_bf16(
                    cA[mf][kf], Bf[nf], acc[mf][nf], 0, 0, 0);
    }

    // ---- op weights + biases (loaded late: cA is dead now) ---------------
    bf16x8 oA[2][2];
    const bf16_t* ow = oppk + (size_t)layer * 128 * 64;
    #pragma unroll
    for (int mf = 0; mf < 2; ++mf)
        #pragma unroll
        for (int kf = 0; kf < 2; ++kf)
            oA[mf][kf] = *(const bf16x8*)(ow + (mf * 64 + wq * 16 + lr) * 64 + kf * 32 + g * 8);

    // ---- gating in-lane, z -> LDS in B-frag layout -----------------------
    int zbase = 49152 + h * 8192;
    #pragma unroll
    for (int nf = 0; nf < 4; ++nf) {
        union { bf16_t hh[4]; uint2 u; } zp;
        #pragma unroll
        for (int r = 0; r < 4; ++r)
            zp.hh[r] = (bf16_t)(fsig(acc[0][nf][r]) * ftanh(acc[1][nf][r]));
        int off = zbase + (nf * 16 + lr) * 128 + (wq * 16 + g * 4) * 2;
        *(uint2*)(sm + swz(off)) = zp.u;
    }
    __syncthreads();                                      // barrier 2: z ready

    // ---- op 1x1 GEMM ------------------------------------------------------
    f32x4 acc2[2][4];
    const float* ob = op_b + layer * 2 * C;
    #pragma unroll
    for (int mf = 0; mf < 2; ++mf) {
        f32x4 bv;
        #pragma unroll
        for (int r = 0; r < 4; ++r) bv[r] = ob[mf * 64 + wq * 16 + g * 4 + r];
        #pragma unroll
        for (int nf = 0; nf < 4; ++nf) acc2[mf][nf] = bv;
    }
    #pragma unroll
    for (int kf = 0; kf < 2; ++kf) {
        bf16x8 Zf[4];
        #pragma unroll
        for (int nf = 0; nf < 4; ++nf) {
            int off = zbase + (nf * 16 + lr) * 128 + (kf * 32 + g * 8) * 2;
            Zf[nf] = *(const bf16x8*)(sm + swz(off));
        }
        #pragma unroll
        for (int mf = 0; mf < 2; ++mf)
            #pragma unroll
            for (int nf = 0; nf < 4; ++nf)
                acc2[mf][nf] = __builtin_amdgcn_mfma_f32_16x16x32_bf16(
                    oA[mf][kf], Zf[nf], acc2[mf][nf], 0, 0, 0);
    }

    // ---- epilogue: residual + skip, [t][c] bf16 --------------------------
    size_t bb = (size_t)b * T * 64;
    int t0 = tbase + h * 64;
    #pragma unroll
    for (int nf = 0; nf < 4; ++nf) {
        int t = t0 + nf * 16 + lr;
        int c0 = wq * 16 + g * 4;
        int xoff = hbase + 8192 + (nf * 16 + lr) * 128 + c0 * 2;   // tap-1 slice
        bf16x4 xv = *(const bf16x4*)(sm + swz(xoff));
        bf16x4 ro, so;
        bf16_t* sp = skip + bb + (size_t)t * 64 + c0;
        if (first) {
            #pragma unroll
            for (int r = 0; r < 4; ++r) {
                ro[r] = (bf16_t)(((float)xv[r] + acc2[0][nf][r]) * INV_SQRT2);
                so[r] = (bf16_t)acc2[1][nf][r];
            }
        } else {
            bf16x4 sv = *(const bf16x4*)sp;
            #pragma unroll
            for (int r = 0; r < 4; ++r) {
                ro[r] = (bf16_t)(((float)xv[r] + acc2[0][nf][r]) * INV_SQRT2);
                so[r] = (bf16_t)((float)sv[r] + acc2[1][nf][r]);
            }
        }
        *(bf16x4*)(x_out + bb + (size_t)t * 64 + c0) = ro;
        *(bf16x4*)sp = so;
    }
}

// ---------------------------------------------------------------------------
// Final: skip(bf16,[t][c]) -> sk conv (MFMA, weights pre-scaled by 1/sqrt30)
// -> relu -> dot with out_W + out_b. Block = 64-t tile, 4 waves each own 16 oc.
// ---------------------------------------------------------------------------
__global__ __launch_bounds__(256) void final_kernel(
    const bf16_t* __restrict__ skip, const bf16_t* __restrict__ skpk,
    const float* __restrict__ sk_b,
    const float* __restrict__ out_W, const float* __restrict__ out_b,
    float* __restrict__ out)
{
    __shared__ uint4 tile_u[512];                       // 8KB tile
    __shared__ float part[16][66];
    unsigned char* sm = (unsigned char*)tile_u;
    int tid = threadIdx.x;
    int w = __builtin_amdgcn_readfirstlane(tid >> 6);
    int l = tid & 63, lr = l & 15, g = l >> 4;
    int b = blockIdx.y, t0 = blockIdx.x * 64;
    const bf16_t* sb = skip + (size_t)b * T * 64;

    #pragma unroll
    for (int it = 0; it < 2; ++it) {
        int q = it * 256 + tid;             // 0..511
        int row = q >> 3, c16 = q & 7;
        uint4 val = *(const uint4*)(sb + (size_t)(t0 + row) * 64 + c16 * 8);
        *(uint4*)(sm + swz(row * 128 + c16 * 16)) = val;
    }

    bf16x8 aS[2];
    #pragma unroll
    for (int kf = 0; kf < 2; ++kf)
        aS[kf] = *(const bf16x8*)(skpk + (w * 16 + lr) * 64 + kf * 32 + g * 8);
    f32x4 acc[4];
    #pragma unroll
    for (int nf = 0; nf < 4; ++nf)
        #pragma unroll
        for (int r = 0; r < 4; ++r) acc[nf][r] = sk_b[w * 16 + g * 4 + r];
    __syncthreads();

    #pragma unroll
    for (int kf = 0; kf < 2; ++kf) {
        bf16x8 Bf[4];
        #pragma unroll
        for (int nf = 0; nf < 4; ++nf) {
            int off = (nf * 16 + lr) * 128 + (kf * 32 + g * 8) * 2;
            Bf[nf] = *(const bf16x8*)(sm + swz(off));
        }
        #pragma unroll
        for (int nf = 0; nf < 4; ++nf)
            acc[nf] = __builtin_amdgcn_mfma_f32_16x16x32_bf16(aS[kf], Bf[nf], acc[nf], 0, 0, 0);
    }

    #pragma unroll
    for (int nf = 0; nf < 4; ++nf) {
        float o = 0.f;
        #pragma unroll
        for (int r = 0; r < 4; ++r)
            o = fmaf(out_W[w * 16 + g * 4 + r], fmaxf(acc[nf][r], 0.f), o);
        part[w * 4 + g][nf * 16 + lr] = o;
    }
    __syncthreads();
    if (tid < 64) {
        float o = out_b[0];
        #pragma unroll
        for (int j = 0; j < 16; ++j) o += part[j][tid];
        out[(size_t)b * T + t0 + tid] = o;
    }
}

// ---------------------------------------------------------------------------
extern "C" void kernel_launch(void* const* d_in, const int* in_sizes, int n_in,
                              void* d_out, int out_size, void* d_ws, size_t ws_size,
                              hipStream_t stream) {
    const float* audio = (const float*)d_in[0];
    const int*   dstep = (const int*)d_in[1];
    const float* in_W  = (const float*)d_in[2];
    const float* in_b  = (const float*)d_in[3];
    const float* p1_W  = (const float*)d_in[4];
    const float* p1_b  = (const float*)d_in[5];
    const float* p2_W  = (const float*)d_in[6];
    const float* p2_b  = (const float*)d_in[7];
    const float* dw_W  = (const float*)d_in[8];
    const float* dw_b  = (const float*)d_in[9];
    const float* dp_W  = (const float*)d_in[10];
    const float* dp_b  = (const float*)d_in[11];
    const float* op_W  = (const float*)d_in[12];
    const float* op_b  = (const float*)d_in[13];
    const float* sk_W  = (const float*)d_in[14];
    const float* sk_b  = (const float*)d_in[15];
    const float* out_W = (const float*)d_in[16];
    const float* out_b = (const float*)d_in[17];

    float* ws = (float*)d_ws;
    const size_t NXE = (size_t)B * T * 64;             // elems per activation buf
    float* h1    = ws;                                  // B*512
    float* h2    = h1 + B * 512;                        // B*512
    float* bias2 = h2 + B * 512;                        // NL*B*128
    float* zpg   = bias2 + NL * B * 128;                // 128 floats (512B zero page)
    bf16_t* xA   = (bf16_t*)(zpg + 128);
    bf16_t* xB   = xA + NXE;
    bf16_t* skip = xB + NXE;
    bf16_t* convpk = skip + NXE;                        // NL*128*192
    bf16_t* oppk   = convpk + (size_t)NL * 128 * 192;   // NL*128*64
    bf16_t* skpk   = oppk + (size_t)NL * 128 * 64;      // 4096

    hipMemsetAsync(zpg, 0, 512, stream);
    hipLaunchKernelGGL(pack_weights, dim3(3856), dim3(256), 0, stream,
                       dw_W, op_W, sk_W, convpk, oppk, skpk);
    hipLaunchKernelGGL(cond_embp1, dim3(B, 8), dim3(256), 0, stream,
                       dstep, p1_W, p1_b, h1);
    hipLaunchKernelGGL(cond_p2, dim3(B, 8), dim3(256), 0, stream,
                       h1, p2_W, p2_b, h2);
    hipLaunchKernelGGL(cond_stage2b, dim3(NL, B), dim3(256), 0, stream,
                       h2, dp_W, dp_b, convpk, dw_b, bias2);
    hipLaunchKernelGGL(in_conv, dim3(B * T * 8 / 256), dim3(256), 0, stream,
                       audio, in_W, in_b, xA);
    for (int i = 0; i < NL; ++i) {
        bf16_t* xin  = (i & 1) ? xB : xA;
        bf16_t* xout = (i & 1) ? xA : xB;
        int dil = 1 << (i % 10);
        hipLaunchKernelGGL(layer_kernel, dim3(T / 128, B), dim3(512), 0, stream,
                           xin, xout, skip, convpk, oppk, bias2, op_b,
                           (const bf16_t*)zpg, i, dil, (i == 0) ? 1 : 0);
    }
    hipLaunchKernelGGL(final_kernel, dim3(T / 64, B), dim3(256), 0, stream,
                       skip, skpk, sk_b, out_W, out_b, (float*)d_out);
}

// Round 7
// 514.149 us; speedup vs baseline: 1.0590x; 1.0590x over previous
//
#include <hip/hip_runtime.h>
#include <math.h>

#define C 64
#define NL 30
#define T 16384
#define B 4

typedef __bf16 bf16_t;
typedef __bf16 bf16x8 __attribute__((ext_vector_type(8)));
typedef __bf16 bf16x4 __attribute__((ext_vector_type(4)));
typedef float f32x4 __attribute__((ext_vector_type(4)));

typedef const __attribute__((address_space(1))) unsigned int glb_u32;
typedef __attribute__((address_space(3))) unsigned int lds_u32;

constexpr float INV_SQRT2   = 0.70710678118654752440f;
constexpr float INV_SQRT_NL = 0.18257418583505537115f; // 1/sqrt(30)

__device__ __forceinline__ float fsig(float x) {
    return __builtin_amdgcn_rcpf(1.f + __builtin_amdgcn_exp2f(-1.44269504089f * x));
}
__device__ __forceinline__ float ftanh(float x) {
    return fmaf(2.f, __builtin_amdgcn_rcpf(1.f + __builtin_amdgcn_exp2f(-2.88539008178f * x)), -1.f);
}
// XOR swizzle for 128-byte-row LDS tiles (G4): byte ^= ((row&7)<<4)
__device__ __forceinline__ int swz(int off) { return off ^ ((off >> 3) & 0x70); }

// ---------------------------------------------------------------------------
// Pack weights to bf16 K-contiguous rows:
//   convpk[l][oc][k], k = tap*64+ic ; oppk[l][oc][ic] ; skpk[oc][ic]*1/sqrt(30)
// ---------------------------------------------------------------------------
__global__ void pack_weights(const float* __restrict__ dw_W,
                             const float* __restrict__ op_W,
                             const float* __restrict__ sk_W,
                             bf16_t* __restrict__ convpk,
                             bf16_t* __restrict__ oppk,
                             bf16_t* __restrict__ skpk) {
    int idx = blockIdx.x * 256 + threadIdx.x;
    const int ndw = NL * 128 * 192;
    const int nop = NL * 128 * 64;
    if (idx < ndw) {
        int k = idx % 192; int r = idx / 192;
        int oc = r % 128;  int l = r / 128;
        int tap = k >> 6, ic = k & 63;
        convpk[idx] = (bf16_t)dw_W[((l * 128 + oc) * 64 + ic) * 3 + tap];
    } else if (idx < ndw + nop) {
        oppk[idx - ndw] = (bf16_t)op_W[idx - ndw];
    } else if (idx < ndw + nop + 4096) {
        int j = idx - ndw - nop;
        skpk[j] = (bf16_t)(sk_W[j] * INV_SQRT_NL);
    }
}

// ---------------------------------------------------------------------------
// Cond: emb -> p1 (silu). grid (B, 8): block owns 64 outputs, 4-way split-K.
// ---------------------------------------------------------------------------
__global__ void cond_embp1(const int* __restrict__ step,
                           const float* __restrict__ p1_W, const float* __restrict__ p1_b,
                           float* __restrict__ h1out) {
    __shared__ float e[128];
    __shared__ float red[256];
    int b = blockIdx.x, blk = blockIdx.y, tid = threadIdx.x;
    int s = step[b];
    if (tid < 128) {
        int d = tid & 63;
        float tf = (float)s * powf(10.f, (float)d * 4.f / 63.f);
        double td = (double)tf;
        e[tid] = (tid < 64) ? (float)sin(td) : (float)cos(td);
    }
    __syncthreads();
    int ol = tid >> 2, q = tid & 3;
    int o = blk * 64 + ol;
    const float4* wr = (const float4*)(p1_W + o * 128 + q * 32);
    const float4* ev = (const float4*)(e + q * 32);
    float a = 0.f;
    #pragma unroll
    for (int j = 0; j < 8; ++j) {
        float4 wv = wr[j]; float4 xv = ev[j];
        a = fmaf(wv.x, xv.x, a); a = fmaf(wv.y, xv.y, a);
        a = fmaf(wv.z, xv.z, a); a = fmaf(wv.w, xv.w, a);
    }
    red[tid] = a;
    __syncthreads();
    if (q == 0) {
        float v = red[tid] + red[tid + 1] + red[tid + 2] + red[tid + 3] + p1_b[o];
        h1out[b * 512 + o] = v / (1.f + expf(-v));
    }
}

// ---------------------------------------------------------------------------
// Cond: p2 (silu). grid (B, 8): block owns 64 outputs, 4-way split-K (K=512).
// ---------------------------------------------------------------------------
__global__ void cond_p2(const float* __restrict__ h1,
                        const float* __restrict__ p2_W, const float* __restrict__ p2_b,
                        float* __restrict__ h2out) {
    __shared__ float red[256];
    int b = blockIdx.x, blk = blockIdx.y, tid = threadIdx.x;
    int ol = tid >> 2, q = tid & 3;
    int o = blk * 64 + ol;
    const float4* wr = (const float4*)(p2_W + o * 512 + q * 128);
    const float4* hv = (const float4*)(h1 + b * 512 + q * 128);
    float a = 0.f;
    #pragma unroll 8
    for (int j = 0; j < 32; ++j) {
        float4 wv = wr[j]; float4 xv = hv[j];
        a = fmaf(wv.x, xv.x, a); a = fmaf(wv.y, xv.y, a);
        a = fmaf(wv.z, xv.z, a); a = fmaf(wv.w, xv.w, a);
    }
    red[tid] = a;
    __syncthreads();
    if (q == 0) {
        float v = red[tid] + red[tid + 1] + red[tid + 2] + red[tid + 3] + p2_b[o];
        h2out[b * 512 + o] = v / (1.f + expf(-v));
    }
}

// ---------------------------------------------------------------------------
// Fused: cond projection + fold into conv bias.
//   cond[c]       = dp_W[l] @ h2[b] + dp_b[l]         (LDS only)
//   bias2[l][b][o]= dw_b[l][o] + sum_k convpk[l][o][k] * cond[k&63]
// grid (NL, B), 256 threads.
// ---------------------------------------------------------------------------
__global__ void cond_stage2b(const float* __restrict__ h2,
                             const float* __restrict__ dp_W, const float* __restrict__ dp_b,
                             const bf16_t* __restrict__ convpk,
                             const float* __restrict__ dw_b,
                             float* __restrict__ bias2) {
    __shared__ float red[256];
    __shared__ float cond_s[64];
    int l = blockIdx.x, b = blockIdx.y;
    int tid = threadIdx.x;
    {
        int o = tid >> 2, q = tid & 3;
        const float4* wr = (const float4*)(dp_W + ((size_t)l * C + o) * 512 + q * 128);
        const float4* h = (const float4*)(h2 + b * 512 + q * 128);
        float a = 0.f;
        #pragma unroll 8
        for (int j = 0; j < 32; ++j) {
            float4 wv = wr[j]; float4 hv = h[j];
            a = fmaf(wv.x, hv.x, a); a = fmaf(wv.y, hv.y, a);
            a = fmaf(wv.z, hv.z, a); a = fmaf(wv.w, hv.w, a);
        }
        red[tid] = a;
        __syncthreads();
        if (q == 0)
            cond_s[o] = red[tid] + red[tid + 1] + red[tid + 2] + red[tid + 3] + dp_b[l * C + o];
    }
    __syncthreads();
    int oc = tid & 127, kh = tid >> 7;
    const bf16_t* wr = convpk + ((size_t)l * 128 + oc) * 192 + kh * 96;
    float a = kh ? 0.f : dw_b[l * 128 + oc];
    #pragma unroll
    for (int j = 0; j < 96; ++j)
        a = fmaf((float)wr[j], cond_s[(kh * 96 + j) & 63], a);
    __syncthreads();
    red[tid] = a;
    __syncthreads();
    if (tid < 128)
        bias2[(l * B + b) * 128 + tid] = red[tid] + red[tid + 128];
}

// ---------------------------------------------------------------------------
// Input 1x1 conv + ReLU -> x[b][t][c] bf16. Thread handles 8 channels.
// ---------------------------------------------------------------------------
__global__ void in_conv(const float* __restrict__ audio,
                        const float* __restrict__ in_W, const float* __restrict__ in_b,
                        bf16_t* __restrict__ x) {
    int idx = blockIdx.x * 256 + threadIdx.x;   // over B*T*8
    int cb = idx & 7;
    int t = (idx >> 3) & (T - 1);
    int b = idx >> 17;
    float av = audio[b * T + t];
    bf16x8 o;
    #pragma unroll
    for (int j = 0; j < 8; ++j) {
        int c = cb * 8 + j;
        o[j] = (bf16_t)fmaxf(fmaf(in_W[c], av, in_b[c]), 0.f);
    }
    *(bf16x8*)(x + ((size_t)b * T + t) * 64 + cb * 8) = o;
}

// ---------------------------------------------------------------------------
// One residual layer (R5 structure + T4-lite pipeline + single-slab staging
// for dil<=32). 256 thr = 4 waves; block = 128 t as 2 sequential sub-tiles.
// Wave wq owns conv rows {wq*16..+16} (gate) and {64+wq*16..+16} (filt):
// gate/filt pair sits in the same lane/reg -> no exchange.
// Staging: BOTH sub-tiles issued up front via global_load_lds(16B), source-
// swizzled (c16 ^= row&7), linear LDS dest; then s_waitcnt vmcnt(N1)+s_barrier
// so sub-tile 1's loads stay in flight under sub-tile 0's compute.
// LDS: S0 @0 (24KB), S1 @24576 (24KB), z0 @49152 (8KB), z1 @57344 (8KB).
//   dil<=32: S holds single slab rows [t0-d, ...) (row = t_local + tap*d)
//   dil>32 : S holds 3 shifted 64-row slices (8KB each)
// ---------------------------------------------------------------------------
__global__ __launch_bounds__(256) void layer_kernel(
    const bf16_t* __restrict__ x_in, bf16_t* __restrict__ x_out, bf16_t* __restrict__ skip,
    const bf16_t* __restrict__ convpk, const bf16_t* __restrict__ oppk,
    const float* __restrict__ bias2, const float* __restrict__ op_b,
    const bf16_t* __restrict__ zpage,
    int layer, int dil, int first)
{
    __shared__ uint4 smem_u[4096];                       // 65536 B
    char* sm = (char*)smem_u;

    int tid = threadIdx.x;
    int w = __builtin_amdgcn_readfirstlane(tid >> 6);    // wave id 0..3
    int l = tid & 63;
    int lr = l & 15;
    int g = l >> 4;
    int b = blockIdx.y;
    int tbase = blockIdx.x * 128;
    const bf16_t* xb = x_in + (size_t)b * T * 64;
    const bool m1 = (dil <= 32);

    // ---- issue staging for BOTH sub-tiles (nothing else touches VMEM first)
    // single-slab mode: R rounds of 4KB; rows [t0s-d, t0s-d+32R)
#define STAGE_M1(Sbase, t0s, R)                                              \
    _Pragma("unroll")                                                        \
    for (int r = 0; r < (R); ++r) {                                          \
        int q = r * 4096 + tid * 16;                                         \
        int row = q >> 7, c16 = (q >> 4) & 7;                                \
        int ts = (t0s) - dil + row;                                          \
        int c16s = c16 ^ (row & 7);                                          \
        const bf16_t* src = ((unsigned)ts < (unsigned)T)                     \
            ? xb + (size_t)ts * 64 + c16s * 8 : zpage + c16s * 8;            \
        __builtin_amdgcn_global_load_lds((glb_u32*)src,                      \
            (lds_u32*)(sm + (Sbase) + r * 4096 + w * 1024), 16, 0, 0);       \
    }
    // 3-slice mode: 6 rounds of 4KB (slice = 8KB of 64 rows)
#define STAGE_M3(Sbase, t0s)                                                 \
    _Pragma("unroll")                                                        \
    for (int it = 0; it < 6; ++it) {                                         \
        int qq = it * 256 + tid;                                             \
        int slice = qq >> 9, row = (qq >> 3) & 63, c16 = qq & 7;             \
        int ts = (t0s) + row + (slice - 1) * dil;                            \
        int c16s = c16 ^ (row & 7);                                          \
        const bf16_t* src = ((unsigned)ts < (unsigned)T)                     \
            ? xb + (size_t)ts * 64 + c16s * 8 : zpage + c16s * 8;            \
        __builtin_amdgcn_global_load_lds((glb_u32*)src,                      \
            (lds_u32*)(sm + (Sbase) + it * 4096 + w * 1024), 16, 0, 0);      \
    }

    if (dil <= 16) {            // rows needed: 64+2d <= 96 -> 3 rounds
        STAGE_M1(0, tbase, 3)
        STAGE_M1(24576, tbase + 64, 3)
        asm volatile("s_waitcnt vmcnt(3)" ::: "memory");
    } else if (dil == 32) {     // rows needed: 128 -> 4 rounds
        STAGE_M1(0, tbase, 4)
        STAGE_M1(24576, tbase + 64, 4)
        asm volatile("s_waitcnt vmcnt(4)" ::: "memory");
    } else {
        STAGE_M3(0, tbase)
        STAGE_M3(24576, tbase + 64)
        asm volatile("s_waitcnt vmcnt(6)" ::: "memory");
    }
    __builtin_amdgcn_s_barrier();            // sub-tile 0 staged; 1 in flight
    __builtin_amdgcn_sched_barrier(0);
    asm volatile("" ::: "memory");

    // ---- weights + biases (after the counted wait so vmcnt math is exact)
    bf16x8 cA[2][6];
    const bf16_t* cw = convpk + (size_t)layer * 128 * 192;
    #pragma unroll
    for (int mf = 0; mf < 2; ++mf)
        #pragma unroll
        for (int kf = 0; kf < 6; ++kf)
            cA[mf][kf] = *(const bf16x8*)(cw + (mf * 64 + w * 16 + lr) * 192 + kf * 32 + g * 8);
    bf16x8 oA[2][2];
    const bf16_t* ow = oppk + (size_t)layer * 128 * 64;
    #pragma unroll
    for (int mf = 0; mf < 2; ++mf)
        #pragma unroll
        for (int kf = 0; kf < 2; ++kf)
            oA[mf][kf] = *(const bf16x8*)(ow + (mf * 64 + w * 16 + lr) * 64 + kf * 32 + g * 8);
    f32x4 bC[2], bO[2];
    const float* b2 = bias2 + (layer * B + b) * 128;
    const float* ob = op_b + layer * 2 * C;
    #pragma unroll
    for (int mf = 0; mf < 2; ++mf)
        #pragma unroll
        for (int r = 0; r < 4; ++r) {
            bC[mf][r] = b2[mf * 64 + w * 16 + g * 4 + r];
            bO[mf][r] = ob[mf * 64 + w * 16 + g * 4 + r];
        }

    size_t bb = (size_t)b * T * 64;
    int tapstride = m1 ? dil * 128 : 8192;   // byte stride between taps
    int t1off = m1 ? dil * 128 : 8192;       // tap-1 row base (x_in re-read)

    for (int st = 0; st < 2; ++st) {
        int Sb = st * 24576;
        int zb = 49152 + st * 8192;
        int t0 = tbase + st * 64;

        // ---- conv GEMM: K = 3 taps x 64 c --------------------------------
        f32x4 acc[2][4];
        #pragma unroll
        for (int mf = 0; mf < 2; ++mf)
            #pragma unroll
            for (int nf = 0; nf < 4; ++nf) acc[mf][nf] = bC[mf];
        #pragma unroll
        for (int kf = 0; kf < 6; ++kf) {
            int tap = kf >> 1;
            int kc = (kf & 1) * 32;
            bf16x8 Bf[4];
            #pragma unroll
            for (int nf = 0; nf < 4; ++nf) {
                int off = Sb + tap * tapstride + (nf * 16 + lr) * 128 + (kc + g * 8) * 2;
                Bf[nf] = *(const bf16x8*)(sm + swz(off));
            }
            #pragma unroll
            for (int mf = 0; mf < 2; ++mf)
                #pragma unroll
                for (int nf = 0; nf < 4; ++nf)
                    acc[mf][nf] = __builtin_amdgcn_mfma_f32_16x16x32_bf16(
                        cA[mf][kf], Bf[nf], acc[mf][nf], 0, 0, 0);
        }

        // ---- gating in-lane, z -> LDS in B-frag layout -------------------
        #pragma unroll
        for (int nf = 0; nf < 4; ++nf) {
            union { bf16_t hh[4]; uint2 u; } zp;
            #pragma unroll
            for (int r = 0; r < 4; ++r)
                zp.hh[r] = (bf16_t)(fsig(acc[0][nf][r]) * ftanh(acc[1][nf][r]));
            int off = zb + (nf * 16 + lr) * 128 + (w * 16 + g * 4) * 2;
            *(uint2*)(sm + swz(off)) = zp.u;
        }
        __syncthreads();   // z[st] ready; for st==0 also drains sub-tile 1 loads

        // ---- op 1x1 GEMM --------------------------------------------------
        f32x4 acc2[2][4];
        #pragma unroll
        for (int mf = 0; mf < 2; ++mf)
            #pragma unroll
            for (int nf = 0; nf < 4; ++nf) acc2[mf][nf] = bO[mf];
        #pragma unroll
        for (int kf = 0; kf < 2; ++kf) {
            bf16x8 Zf[4];
            #pragma unroll
            for (int nf = 0; nf < 4; ++nf) {
                int off = zb + (nf * 16 + lr) * 128 + (kf * 32 + g * 8) * 2;
                Zf[nf] = *(const bf16x8*)(sm + swz(off));
            }
            #pragma unroll
            for (int mf = 0; mf < 2; ++mf)
                #pragma unroll
                for (int nf = 0; nf < 4; ++nf)
                    acc2[mf][nf] = __builtin_amdgcn_mfma_f32_16x16x32_bf16(
                        oA[mf][kf], Zf[nf], acc2[mf][nf], 0, 0, 0);
        }

        // ---- epilogue: residual + skip, [t][c] bf16 ----------------------
        #pragma unroll
        for (int nf = 0; nf < 4; ++nf) {
            int t = t0 + nf * 16 + lr;
            int c0 = w * 16 + g * 4;
            int xoff = Sb + t1off + (nf * 16 + lr) * 128 + c0 * 2;  // tap-1 row
            bf16x4 xv = *(const bf16x4*)(sm + swz(xoff));
            bf16x4 ro, so;
            bf16_t* sp = skip + bb + (size_t)t * 64 + c0;
            if (first) {
                #pragma unroll
                for (int r = 0; r < 4; ++r) {
                    ro[r] = (bf16_t)(((float)xv[r] + acc2[0][nf][r]) * INV_SQRT2);
                    so[r] = (bf16_t)acc2[1][nf][r];
                }
            } else {
                bf16x4 sv = *(const bf16x4*)sp;
                #pragma unroll
                for (int r = 0; r < 4; ++r) {
                    ro[r] = (bf16_t)(((float)xv[r] + acc2[0][nf][r]) * INV_SQRT2);
                    so[r] = (bf16_t)((float)sv[r] + acc2[1][nf][r]);
                }
            }
            *(bf16x4*)(x_out + bb + (size_t)t * 64 + c0) = ro;
            *(bf16x4*)sp = so;
        }
        // no extra barrier: sub-tile 1 uses S1/z1, disjoint from S0/z0
    }
#undef STAGE_M1
#undef STAGE_M3
}

// ---------------------------------------------------------------------------
// Final: skip(bf16,[t][c]) -> sk conv (MFMA, weights pre-scaled by 1/sqrt30)
// -> relu -> dot with out_W + out_b. Block = 64-t tile, 4 waves each own 16 oc.
// ---------------------------------------------------------------------------
__global__ __launch_bounds__(256) void final_kernel(
    const bf16_t* __restrict__ skip, const bf16_t* __restrict__ skpk,
    const float* __restrict__ sk_b,
    const float* __restrict__ out_W, const float* __restrict__ out_b,
    float* __restrict__ out)
{
    __shared__ uint4 tile_u[512];                       // 8KB tile
    __shared__ float part[16][66];
    unsigned char* sm = (unsigned char*)tile_u;
    int tid = threadIdx.x;
    int w = __builtin_amdgcn_readfirstlane(tid >> 6);
    int l = tid & 63, lr = l & 15, g = l >> 4;
    int b = blockIdx.y, t0 = blockIdx.x * 64;
    const bf16_t* sb = skip + (size_t)b * T * 64;

    #pragma unroll
    for (int it = 0; it < 2; ++it) {
        int q = it * 256 + tid;             // 0..511
        int row = q >> 3, c16 = q & 7;
        uint4 val = *(const uint4*)(sb + (size_t)(t0 + row) * 64 + c16 * 8);
        *(uint4*)(sm + swz(row * 128 + c16 * 16)) = val;
    }

    bf16x8 aS[2];
    #pragma unroll
    for (int kf = 0; kf < 2; ++kf)
        aS[kf] = *(const bf16x8*)(skpk + (w * 16 + lr) * 64 + kf * 32 + g * 8);
    f32x4 acc[4];
    #pragma unroll
    for (int nf = 0; nf < 4; ++nf)
        #pragma unroll
        for (int r = 0; r < 4; ++r) acc[nf][r] = sk_b[w * 16 + g * 4 + r];
    __syncthreads();

    #pragma unroll
    for (int kf = 0; kf < 2; ++kf) {
        bf16x8 Bf[4];
        #pragma unroll
        for (int nf = 0; nf < 4; ++nf) {
            int off = (nf * 16 + lr) * 128 + (kf * 32 + g * 8) * 2;
            Bf[nf] = *(const bf16x8*)(sm + swz(off));
        }
        #pragma unroll
        for (int nf = 0; nf < 4; ++nf)
            acc[nf] = __builtin_amdgcn_mfma_f32_16x16x32_bf16(aS[kf], Bf[nf], acc[nf], 0, 0, 0);
    }

    #pragma unroll
    for (int nf = 0; nf < 4; ++nf) {
        float o = 0.f;
        #pragma unroll
        for (int r = 0; r < 4; ++r)
            o = fmaf(out_W[w * 16 + g * 4 + r], fmaxf(acc[nf][r], 0.f), o);
        part[w * 4 + g][nf * 16 + lr] = o;
    }
    __syncthreads();
    if (tid < 64) {
        float o = out_b[0];
        #pragma unroll
        for (int j = 0; j < 16; ++j) o += part[j][tid];
        out[(size_t)b * T + t0 + tid] = o;
    }
}

// ---------------------------------------------------------------------------
extern "C" void kernel_launch(void* const* d_in, const int* in_sizes, int n_in,
                              void* d_out, int out_size, void* d_ws, size_t ws_size,
                              hipStream_t stream) {
    const float* audio = (const float*)d_in[0];
    const int*   dstep = (const int*)d_in[1];
    const float* in_W  = (const float*)d_in[2];
    const float* in_b  = (const float*)d_in[3];
    const float* p1_W  = (const float*)d_in[4];
    const float* p1_b  = (const float*)d_in[5];
    const float* p2_W  = (const float*)d_in[6];
    const float* p2_b  = (const float*)d_in[7];
    const float* dw_W  = (const float*)d_in[8];
    const float* dw_b  = (const float*)d_in[9];
    const float* dp_W  = (const float*)d_in[10];
    const float* dp_b  = (const float*)d_in[11];
    const float* op_W  = (const float*)d_in[12];
    const float* op_b  = (const float*)d_in[13];
    const float* sk_W  = (const float*)d_in[14];
    const float* sk_b  = (const float*)d_in[15];
    const float* out_W = (const float*)d_in[16];
    const float* out_b = (const float*)d_in[17];

    float* ws = (float*)d_ws;
    const size_t NXE = (size_t)B * T * 64;             // elems per activation buf
    float* h1    = ws;                                  // B*512
    float* h2    = h1 + B * 512;                        // B*512
    float* bias2 = h2 + B * 512;                        // NL*B*128
    float* zpg   = bias2 + NL * B * 128;                // 128 floats (512B zero page)
    bf16_t* xA   = (bf16_t*)(zpg + 128);
    bf16_t* xB   = xA + NXE;
    bf16_t* skip = xB + NXE;
    bf16_t* convpk = skip + NXE;                        // NL*128*192
    bf16_t* oppk   = convpk + (size_t)NL * 128 * 192;   // NL*128*64
    bf16_t* skpk   = oppk + (size_t)NL * 128 * 64;      // 4096

    hipMemsetAsync(zpg, 0, 512, stream);
    hipLaunchKernelGGL(pack_weights, dim3(3856), dim3(256), 0, stream,
                       dw_W, op_W, sk_W, convpk, oppk, skpk);
    hipLaunchKernelGGL(cond_embp1, dim3(B, 8), dim3(256), 0, stream,
                       dstep, p1_W, p1_b, h1);
    hipLaunchKernelGGL(cond_p2, dim3(B, 8), dim3(256), 0, stream,
                       h1, p2_W, p2_b, h2);
    hipLaunchKernelGGL(cond_stage2b, dim3(NL, B), dim3(256), 0, stream,
                       h2, dp_W, dp_b, convpk, dw_b, bias2);
    hipLaunchKernelGGL(in_conv, dim3(B * T * 8 / 256), dim3(256), 0, stream,
                       audio, in_W, in_b, xA);
    for (int i = 0; i < NL; ++i) {
        bf16_t* xin  = (i & 1) ? xB : xA;
        bf16_t* xout = (i & 1) ? xA : xB;
        int dil = 1 << (i % 10);
        hipLaunchKernelGGL(layer_kernel, dim3(T / 128, B), dim3(256), 0, stream,
                           xin, xout, skip, convpk, oppk, bias2, op_b,
                           (const bf16_t*)zpg, i, dil, (i == 0) ? 1 : 0);
    }
    hipLaunchKernelGGL(final_kernel, dim3(T / 64, B), dim3(256), 0, stream,
                       skip, skpk, sk_b, out_W, out_b, (float*)d_out);
}

// Round 8
// 499.488 us; speedup vs baseline: 1.0901x; 1.0294x over previous
//
#include <hip/hip_runtime.h>
#include <math.h>

#define C 64
#define NL 30
#define T 16384
#define B 4

typedef __bf16 bf16_t;
typedef __bf16 bf16x8 __attribute__((ext_vector_type(8)));
typedef __bf16 bf16x4 __attribute__((ext_vector_type(4)));
typedef float f32x4 __attribute__((ext_vector_type(4)));

typedef const __attribute__((address_space(1))) unsigned int glb_u32;
typedef __attribute__((address_space(3))) unsigned int lds_u32;

constexpr float INV_SQRT2   = 0.70710678118654752440f;
constexpr float INV_SQRT_NL = 0.18257418583505537115f; // 1/sqrt(30)

__device__ __forceinline__ float fsig(float x) {
    return __builtin_amdgcn_rcpf(1.f + __builtin_amdgcn_exp2f(-1.44269504089f * x));
}
__device__ __forceinline__ float ftanh(float x) {
    return fmaf(2.f, __builtin_amdgcn_rcpf(1.f + __builtin_amdgcn_exp2f(-2.88539008178f * x)), -1.f);
}
// XOR swizzle for 128-byte-row LDS tiles (G4): byte ^= ((row&7)<<4)
__device__ __forceinline__ int swz(int off) { return off ^ ((off >> 3) & 0x70); }

// ---------------------------------------------------------------------------
// Pack weights to bf16 K-contiguous rows:
//   convpk[l][oc][k], k = tap*64+ic ; oppk[l][oc][ic] ; skpk[oc][ic]*1/sqrt(30)
// ---------------------------------------------------------------------------
__global__ void pack_weights(const float* __restrict__ dw_W,
                             const float* __restrict__ op_W,
                             const float* __restrict__ sk_W,
                             bf16_t* __restrict__ convpk,
                             bf16_t* __restrict__ oppk,
                             bf16_t* __restrict__ skpk) {
    int idx = blockIdx.x * 256 + threadIdx.x;
    const int ndw = NL * 128 * 192;
    const int nop = NL * 128 * 64;
    if (idx < ndw) {
        int k = idx % 192; int r = idx / 192;
        int oc = r % 128;  int l = r / 128;
        int tap = k >> 6, ic = k & 63;
        convpk[idx] = (bf16_t)dw_W[((l * 128 + oc) * 64 + ic) * 3 + tap];
    } else if (idx < ndw + nop) {
        oppk[idx - ndw] = (bf16_t)op_W[idx - ndw];
    } else if (idx < ndw + nop + 4096) {
        int j = idx - ndw - nop;
        skpk[j] = (bf16_t)(sk_W[j] * INV_SQRT_NL);
    }
}

// ---------------------------------------------------------------------------
// Cond: emb -> p1 (silu). grid (B, 8): block owns 64 outputs, 4-way split-K.
// ---------------------------------------------------------------------------
__global__ void cond_embp1(const int* __restrict__ step,
                           const float* __restrict__ p1_W, const float* __restrict__ p1_b,
                           float* __restrict__ h1out) {
    __shared__ float e[128];
    __shared__ float red[256];
    int b = blockIdx.x, blk = blockIdx.y, tid = threadIdx.x;
    int s = step[b];
    if (tid < 128) {
        int d = tid & 63;
        float tf = (float)s * powf(10.f, (float)d * 4.f / 63.f);
        double td = (double)tf;
        e[tid] = (tid < 64) ? (float)sin(td) : (float)cos(td);
    }
    __syncthreads();
    int ol = tid >> 2, q = tid & 3;
    int o = blk * 64 + ol;
    const float4* wr = (const float4*)(p1_W + o * 128 + q * 32);
    const float4* ev = (const float4*)(e + q * 32);
    float a = 0.f;
    #pragma unroll
    for (int j = 0; j < 8; ++j) {
        float4 wv = wr[j]; float4 xv = ev[j];
        a = fmaf(wv.x, xv.x, a); a = fmaf(wv.y, xv.y, a);
        a = fmaf(wv.z, xv.z, a); a = fmaf(wv.w, xv.w, a);
    }
    red[tid] = a;
    __syncthreads();
    if (q == 0) {
        float v = red[tid] + red[tid + 1] + red[tid + 2] + red[tid + 3] + p1_b[o];
        h1out[b * 512 + o] = v / (1.f + expf(-v));
    }
}

// ---------------------------------------------------------------------------
// Cond: p2 (silu). grid (B, 8): block owns 64 outputs, 4-way split-K (K=512).
// ---------------------------------------------------------------------------
__global__ void cond_p2(const float* __restrict__ h1,
                        const float* __restrict__ p2_W, const float* __restrict__ p2_b,
                        float* __restrict__ h2out) {
    __shared__ float red[256];
    int b = blockIdx.x, blk = blockIdx.y, tid = threadIdx.x;
    int ol = tid >> 2, q = tid & 3;
    int o = blk * 64 + ol;
    const float4* wr = (const float4*)(p2_W + o * 512 + q * 128);
    const float4* hv = (const float4*)(h1 + b * 512 + q * 128);
    float a = 0.f;
    #pragma unroll 8
    for (int j = 0; j < 32; ++j) {
        float4 wv = wr[j]; float4 xv = hv[j];
        a = fmaf(wv.x, xv.x, a); a = fmaf(wv.y, xv.y, a);
        a = fmaf(wv.z, xv.z, a); a = fmaf(wv.w, xv.w, a);
    }
    red[tid] = a;
    __syncthreads();
    if (q == 0) {
        float v = red[tid] + red[tid + 1] + red[tid + 2] + red[tid + 3] + p2_b[o];
        h2out[b * 512 + o] = v / (1.f + expf(-v));
    }
}

// ---------------------------------------------------------------------------
// Fused: cond projection + fold into conv bias.
//   cond[c]       = dp_W[l] @ h2[b] + dp_b[l]         (LDS only)
//   bias2[l][b][o]= dw_b[l][o] + sum_k convpk[l][o][k] * cond[k&63]
// grid (NL, B), 256 threads.
// ---------------------------------------------------------------------------
__global__ void cond_stage2b(const float* __restrict__ h2,
                             const float* __restrict__ dp_W, const float* __restrict__ dp_b,
                             const bf16_t* __restrict__ convpk,
                             const float* __restrict__ dw_b,
                             float* __restrict__ bias2) {
    __shared__ float red[256];
    __shared__ float cond_s[64];
    int l = blockIdx.x, b = blockIdx.y;
    int tid = threadIdx.x;
    {
        int o = tid >> 2, q = tid & 3;
        const float4* wr = (const float4*)(dp_W + ((size_t)l * C + o) * 512 + q * 128);
        const float4* h = (const float4*)(h2 + b * 512 + q * 128);
        float a = 0.f;
        #pragma unroll 8
        for (int j = 0; j < 32; ++j) {
            float4 wv = wr[j]; float4 hv = h[j];
            a = fmaf(wv.x, hv.x, a); a = fmaf(wv.y, hv.y, a);
            a = fmaf(wv.z, hv.z, a); a = fmaf(wv.w, hv.w, a);
        }
        red[tid] = a;
        __syncthreads();
        if (q == 0)
            cond_s[o] = red[tid] + red[tid + 1] + red[tid + 2] + red[tid + 3] + dp_b[l * C + o];
    }
    __syncthreads();
    int oc = tid & 127, kh = tid >> 7;
    const bf16_t* wr = convpk + ((size_t)l * 128 + oc) * 192 + kh * 96;
    float a = kh ? 0.f : dw_b[l * 128 + oc];
    #pragma unroll
    for (int j = 0; j < 96; ++j)
        a = fmaf((float)wr[j], cond_s[(kh * 96 + j) & 63], a);
    __syncthreads();
    red[tid] = a;
    __syncthreads();
    if (tid < 128)
        bias2[(l * B + b) * 128 + tid] = red[tid] + red[tid + 128];
}

// ---------------------------------------------------------------------------
// Input 1x1 conv + ReLU -> x[b][t][c] bf16. Thread handles 8 channels.
// ---------------------------------------------------------------------------
__global__ void in_conv(const float* __restrict__ audio,
                        const float* __restrict__ in_W, const float* __restrict__ in_b,
                        bf16_t* __restrict__ x) {
    int idx = blockIdx.x * 256 + threadIdx.x;   // over B*T*8
    int cb = idx & 7;
    int t = (idx >> 3) & (T - 1);
    int b = idx >> 17;
    float av = audio[b * T + t];
    bf16x8 o;
    #pragma unroll
    for (int j = 0; j < 8; ++j) {
        int c = cb * 8 + j;
        o[j] = (bf16_t)fmaxf(fmaf(in_W[c], av, in_b[c]), 0.f);
    }
    *(bf16x8*)(x + ((size_t)b * T + t) * 64 + cb * 8) = o;
}

// ---------------------------------------------------------------------------
// One residual layer. x layout [b][t][c] bf16. 256 thr = 4 waves; block =
// 128 t as 2 sub-tiles. Wave w owns conv rows {w*16..+16} (gate) and
// {64+w*16..+16} (filt): gate/filt pair in the same lane -> no exchange.
// DYNAMIC LDS, sized per dilation (occupancy!):
//   d<=16: dual slab  S0@0 12KB | S1@12KB | z@24KB 8KB  -> 32KB, both
//          sub-tiles staged up front, counted vmcnt(3) + raw barrier so
//          sub-tile 1's loads stay in flight under sub-tile 0's compute.
//   d==32: same with 16KB slabs -> 40KB, vmcnt(4).
//   d>32 : R5 path: 3-slice S@0 24KB | z@24KB -> 32KB, stage per sub-tile.
// Staging via global_load_lds(16B): swizzle on the GLOBAL source
// (c16 ^= row&7), linear LDS dest; OOB taps read a zeroed page.
// ---------------------------------------------------------------------------
__global__ __launch_bounds__(256) void layer_kernel(
    const bf16_t* __restrict__ x_in, bf16_t* __restrict__ x_out, bf16_t* __restrict__ skip,
    const bf16_t* __restrict__ convpk, const bf16_t* __restrict__ oppk,
    const float* __restrict__ bias2, const float* __restrict__ op_b,
    const bf16_t* __restrict__ zpage,
    int layer, int dil, int first)
{
    extern __shared__ char sm[];

    int tid = threadIdx.x;
    int w = __builtin_amdgcn_readfirstlane(tid >> 6);    // wave id 0..3
    int l = tid & 63;
    int lr = l & 15;
    int g = l >> 4;
    int b = blockIdx.y;
    int tbase = blockIdx.x * 128;
    const bf16_t* xb = x_in + (size_t)b * T * 64;
    const bool dual = (dil <= 32);
    const int R = (dil <= 16) ? 3 : 4;                   // slab rounds (dual)

    // slab staging: R rounds of 4KB, rows [t0s-d, t0s-d+32R)
#define STAGE_SLAB(Sbase, t0s, RR)                                           \
    _Pragma("unroll")                                                        \
    for (int r = 0; r < (RR); ++r) {                                         \
        int row = r * 32 + (tid >> 3), c16 = tid & 7;                        \
        int ts = (t0s) - dil + row;                                          \
        int c16s = c16 ^ (row & 7);                                          \
        const bf16_t* src = ((unsigned)ts < (unsigned)T)                     \
            ? xb + (size_t)ts * 64 + c16s * 8 : zpage + c16s * 8;            \
        __builtin_amdgcn_global_load_lds((glb_u32*)src,                      \
            (lds_u32*)(sm + (Sbase) + r * 4096 + w * 1024), 16, 0, 0);       \
    }
    // 3-slice staging: 6 rounds of 4KB (slice = 8KB of 64 rows)
#define STAGE_M3(t0s)                                                        \
    _Pragma("unroll")                                                        \
    for (int it = 0; it < 6; ++it) {                                         \
        int qq = it * 256 + tid;                                             \
        int slice = qq >> 9, row = (qq >> 3) & 63, c16 = qq & 7;             \
        int ts = (t0s) + row + (slice - 1) * dil;                            \
        int c16s = c16 ^ (row & 7);                                          \
        const bf16_t* src = ((unsigned)ts < (unsigned)T)                     \
            ? xb + (size_t)ts * 64 + c16s * 8 : zpage + c16s * 8;            \
        __builtin_amdgcn_global_load_lds((glb_u32*)src,                      \
            (lds_u32*)(sm + it * 4096 + w * 1024), 16, 0, 0);                \
    }

    if (dual) {
        // issue BOTH sub-tiles before any other VMEM, then counted wait:
        // after 2R issues, vmcnt(R) = sub-tile 0 complete, sub-tile 1 in flight
        if (dil <= 16) {
            STAGE_SLAB(0, tbase, 3)
            STAGE_SLAB(12288, tbase + 64, 3)
            asm volatile("s_waitcnt vmcnt(3)" ::: "memory");
        } else {
            STAGE_SLAB(0, tbase, 4)
            STAGE_SLAB(16384, tbase + 64, 4)
            asm volatile("s_waitcnt vmcnt(4)" ::: "memory");
        }
        __builtin_amdgcn_s_barrier();
        __builtin_amdgcn_sched_barrier(0);
    }

    // ---- weights + biases (after the counted wait so vmcnt math is exact)
    bf16x8 cA[2][6];
    const bf16_t* cw = convpk + (size_t)layer * 128 * 192;
    #pragma unroll
    for (int mf = 0; mf < 2; ++mf)
        #pragma unroll
        for (int kf = 0; kf < 6; ++kf)
            cA[mf][kf] = *(const bf16x8*)(cw + (mf * 64 + w * 16 + lr) * 192 + kf * 32 + g * 8);
    bf16x8 oA[2][2];
    const bf16_t* ow = oppk + (size_t)layer * 128 * 64;
    #pragma unroll
    for (int mf = 0; mf < 2; ++mf)
        #pragma unroll
        for (int kf = 0; kf < 2; ++kf)
            oA[mf][kf] = *(const bf16x8*)(ow + (mf * 64 + w * 16 + lr) * 64 + kf * 32 + g * 8);
    f32x4 bC[2], bO[2];
    const float* b2 = bias2 + (layer * B + b) * 128;
    const float* ob = op_b + layer * 2 * C;
    #pragma unroll
    for (int mf = 0; mf < 2; ++mf)
        #pragma unroll
        for (int r = 0; r < 4; ++r) {
            bC[mf][r] = b2[mf * 64 + w * 16 + g * 4 + r];
            bO[mf][r] = ob[mf * 64 + w * 16 + g * 4 + r];
        }

    size_t bb = (size_t)b * T * 64;
    const int zb = dual ? 2 * R * 4096 : 24576;     // z tile base
    const int tapstride = dual ? dil * 128 : 8192;  // byte stride between taps

    for (int st = 0; st < 2; ++st) {
        int Sb = dual ? st * R * 4096 : 0;
        int t0 = tbase + st * 64;

        if (!dual) {
            STAGE_M3(t0)
            __syncthreads();                        // stage done
        }

        // ---- conv GEMM: K = 3 taps x 64 c --------------------------------
        f32x4 acc[2][4];
        #pragma unroll
        for (int mf = 0; mf < 2; ++mf)
            #pragma unroll
            for (int nf = 0; nf < 4; ++nf) acc[mf][nf] = bC[mf];
        #pragma unroll
        for (int kf = 0; kf < 6; ++kf) {
            int tap = kf >> 1;
            int kc = (kf & 1) * 32;
            bf16x8 Bf[4];
            #pragma unroll
            for (int nf = 0; nf < 4; ++nf) {
                int off = Sb + tap * tapstride + (nf * 16 + lr) * 128 + (kc + g * 8) * 2;
                Bf[nf] = *(const bf16x8*)(sm + swz(off));
            }
            #pragma unroll
            for (int mf = 0; mf < 2; ++mf)
                #pragma unroll
                for (int nf = 0; nf < 4; ++nf)
                    acc[mf][nf] = __builtin_amdgcn_mfma_f32_16x16x32_bf16(
                        cA[mf][kf], Bf[nf], acc[mf][nf], 0, 0, 0);
        }

        // ---- gating in-lane, z -> LDS in B-frag layout -------------------
        #pragma unroll
        for (int nf = 0; nf < 4; ++nf) {
            union { bf16_t hh[4]; uint2 u; } zp;
            #pragma unroll
            for (int r = 0; r < 4; ++r)
                zp.hh[r] = (bf16_t)(fsig(acc[0][nf][r]) * ftanh(acc[1][nf][r]));
            int off = zb + (nf * 16 + lr) * 128 + (w * 16 + g * 4) * 2;
            *(uint2*)(sm + swz(off)) = zp.u;
        }
        __syncthreads();                            // z ready

        // ---- op 1x1 GEMM --------------------------------------------------
        f32x4 acc2[2][4];
        #pragma unroll
        for (int mf = 0; mf < 2; ++mf)
            #pragma unroll
            for (int nf = 0; nf < 4; ++nf) acc2[mf][nf] = bO[mf];
        #pragma unroll
        for (int kf = 0; kf < 2; ++kf) {
            bf16x8 Zf[4];
            #pragma unroll
            for (int nf = 0; nf < 4; ++nf) {
                int off = zb + (nf * 16 + lr) * 128 + (kf * 32 + g * 8) * 2;
                Zf[nf] = *(const bf16x8*)(sm + swz(off));
            }
            #pragma unroll
            for (int mf = 0; mf < 2; ++mf)
                #pragma unroll
                for (int nf = 0; nf < 4; ++nf)
                    acc2[mf][nf] = __builtin_amdgcn_mfma_f32_16x16x32_bf16(
                        oA[mf][kf], Zf[nf], acc2[mf][nf], 0, 0, 0);
        }

        // ---- epilogue: residual + skip, [t][c] bf16 ----------------------
        #pragma unroll
        for (int nf = 0; nf < 4; ++nf) {
            int t = t0 + nf * 16 + lr;
            int c0 = w * 16 + g * 4;
            int xoff = Sb + tapstride + (nf * 16 + lr) * 128 + c0 * 2;  // tap-1 row
            bf16x4 xv = *(const bf16x4*)(sm + swz(xoff));
            bf16x4 ro, so;
            bf16_t* sp = skip + bb + (size_t)t * 64 + c0;
            if (first) {
                #pragma unroll
                for (int r = 0; r < 4; ++r) {
                    ro[r] = (bf16_t)(((float)xv[r] + acc2[0][nf][r]) * INV_SQRT2);
                    so[r] = (bf16_t)acc2[1][nf][r];
                }
            } else {
                bf16x4 sv = *(const bf16x4*)sp;
                #pragma unroll
                for (int r = 0; r < 4; ++r) {
                    ro[r] = (bf16_t)(((float)xv[r] + acc2[0][nf][r]) * INV_SQRT2);
                    so[r] = (bf16_t)((float)sv[r] + acc2[1][nf][r]);
                }
            }
            *(bf16x4*)(x_out + bb + (size_t)t * 64 + c0) = ro;
            *(bf16x4*)sp = so;
        }
        // barrier before sub-tile 1: frees z, and (dual) guarantees S1
        // loads drained (implied vmcnt(0)) / (!dual) S reusable
        if (st == 0) __syncthreads();
    }
#undef STAGE_SLAB
#undef STAGE_M3
}

// ---------------------------------------------------------------------------
// Final: skip(bf16,[t][c]) -> sk conv (MFMA, weights pre-scaled by 1/sqrt30)
// -> relu -> dot with out_W + out_b. Block = 64-t tile, 4 waves each own 16 oc.
// ---------------------------------------------------------------------------
__global__ __launch_bounds__(256) void final_kernel(
    const bf16_t* __restrict__ skip, const bf16_t* __restrict__ skpk,
    const float* __restrict__ sk_b,
    const float* __restrict__ out_W, const float* __restrict__ out_b,
    float* __restrict__ out)
{
    __shared__ uint4 tile_u[512];                       // 8KB tile
    __shared__ float part[16][66];
    unsigned char* sm = (unsigned char*)tile_u;
    int tid = threadIdx.x;
    int w = __builtin_amdgcn_readfirstlane(tid >> 6);
    int l = tid & 63, lr = l & 15, g = l >> 4;
    int b = blockIdx.y, t0 = blockIdx.x * 64;
    const bf16_t* sb = skip + (size_t)b * T * 64;

    #pragma unroll
    for (int it = 0; it < 2; ++it) {
        int q = it * 256 + tid;             // 0..511
        int row = q >> 3, c16 = q & 7;
        uint4 val = *(const uint4*)(sb + (size_t)(t0 + row) * 64 + c16 * 8);
        *(uint4*)(sm + swz(row * 128 + c16 * 16)) = val;
    }

    bf16x8 aS[2];
    #pragma unroll
    for (int kf = 0; kf < 2; ++kf)
        aS[kf] = *(const bf16x8*)(skpk + (w * 16 + lr) * 64 + kf * 32 + g * 8);
    f32x4 acc[4];
    #pragma unroll
    for (int nf = 0; nf < 4; ++nf)
        #pragma unroll
        for (int r = 0; r < 4; ++r) acc[nf][r] = sk_b[w * 16 + g * 4 + r];
    __syncthreads();

    #pragma unroll
    for (int kf = 0; kf < 2; ++kf) {
        bf16x8 Bf[4];
        #pragma unroll
        for (int nf = 0; nf < 4; ++nf) {
            int off = (nf * 16 + lr) * 128 + (kf * 32 + g * 8) * 2;
            Bf[nf] = *(const bf16x8*)(sm + swz(off));
        }
        #pragma unroll
        for (int nf = 0; nf < 4; ++nf)
            acc[nf] = __builtin_amdgcn_mfma_f32_16x16x32_bf16(aS[kf], Bf[nf], acc[nf], 0, 0, 0);
    }

    #pragma unroll
    for (int nf = 0; nf < 4; ++nf) {
        float o = 0.f;
        #pragma unroll
        for (int r = 0; r < 4; ++r)
            o = fmaf(out_W[w * 16 + g * 4 + r], fmaxf(acc[nf][r], 0.f), o);
        part[w * 4 + g][nf * 16 + lr] = o;
    }
    __syncthreads();
    if (tid < 64) {
        float o = out_b[0];
        #pragma unroll
        for (int j = 0; j < 16; ++j) o += part[j][tid];
        out[(size_t)b * T + t0 + tid] = o;
    }
}

// ---------------------------------------------------------------------------
extern "C" void kernel_launch(void* const* d_in, const int* in_sizes, int n_in,
                              void* d_out, int out_size, void* d_ws, size_t ws_size,
                              hipStream_t stream) {
    const float* audio = (const float*)d_in[0];
    const int*   dstep = (const int*)d_in[1];
    const float* in_W  = (const float*)d_in[2];
    const float* in_b  = (const float*)d_in[3];
    const float* p1_W  = (const float*)d_in[4];
    const float* p1_b  = (const float*)d_in[5];
    const float* p2_W  = (const float*)d_in[6];
    const float* p2_b  = (const float*)d_in[7];
    const float* dw_W  = (const float*)d_in[8];
    const float* dw_b  = (const float*)d_in[9];
    const float* dp_W  = (const float*)d_in[10];
    const float* dp_b  = (const float*)d_in[11];
    const float* op_W  = (const float*)d_in[12];
    const float* op_b  = (const float*)d_in[13];
    const float* sk_W  = (const float*)d_in[14];
    const float* sk_b  = (const float*)d_in[15];
    const float* out_W = (const float*)d_in[16];
    const float* out_b = (const float*)d_in[17];

    float* ws = (float*)d_ws;
    const size_t NXE = (size_t)B * T * 64;             // elems per activation buf
    float* h1    = ws;                                  // B*512
    float* h2    = h1 + B * 512;                        // B*512
    float* bias2 = h2 + B * 512;                        // NL*B*128
    float* zpg   = bias2 + NL * B * 128;                // 128 floats (512B zero page)
    bf16_t* xA   = (bf16_t*)(zpg + 128);
    bf16_t* xB   = xA + NXE;
    bf16_t* skip = xB + NXE;
    bf16_t* convpk = skip + NXE;                        // NL*128*192
    bf16_t* oppk   = convpk + (size_t)NL * 128 * 192;   // NL*128*64
    bf16_t* skpk   = oppk + (size_t)NL * 128 * 64;      // 4096

    hipMemsetAsync(zpg, 0, 512, stream);
    hipLaunchKernelGGL(pack_weights, dim3(3856), dim3(256), 0, stream,
                       dw_W, op_W, sk_W, convpk, oppk, skpk);
    hipLaunchKernelGGL(cond_embp1, dim3(B, 8), dim3(256), 0, stream,
                       dstep, p1_W, p1_b, h1);
    hipLaunchKernelGGL(cond_p2, dim3(B, 8), dim3(256), 0, stream,
                       h1, p2_W, p2_b, h2);
    hipLaunchKernelGGL(cond_stage2b, dim3(NL, B), dim3(256), 0, stream,
                       h2, dp_W, dp_b, convpk, dw_b, bias2);
    hipLaunchKernelGGL(in_conv, dim3(B * T * 8 / 256), dim3(256), 0, stream,
                       audio, in_W, in_b, xA);
    for (int i = 0; i < NL; ++i) {
        bf16_t* xin  = (i & 1) ? xB : xA;
        bf16_t* xout = (i & 1) ? xA : xB;
        int dil = 1 << (i % 10);
        int shmem = (dil <= 16) ? 32768 : (dil <= 32 ? 40960 : 32768);
        hipLaunchKernelGGL(layer_kernel, dim3(T / 128, B), dim3(256), shmem, stream,
                           xin, xout, skip, convpk, oppk, bias2, op_b,
                           (const bf16_t*)zpg, i, dil, (i == 0) ? 1 : 0);
    }
    hipLaunchKernelGGL(final_kernel, dim3(T / 64, B), dim3(256), 0, stream,
                       skip, skpk, sk_b, out_W, out_b, (float*)d_out);
}